// Round 11
// baseline (324.909 us; speedup 1.0000x reference)
//
#include <hip/hip_runtime.h>
#include <math.h>

#define N_NODES 50000
#define N_EDGES 800000
#define D 128
#define NBLK 196   // ceil(N_NODES/256)
#define GATHER_BLOCKS 2048
#define NTILES 1563          // ceil(N_NODES/32)
#define GEMM_CHUNKS 256      // grid = 4*256 = 1024 = 4 blocks/CU -> one resident round

typedef __attribute__((ext_vector_type(8))) short bf16x8;
typedef __attribute__((ext_vector_type(4))) float f32x4;
typedef __attribute__((ext_vector_type(4))) unsigned int u32x4;

static __device__ __forceinline__ unsigned short f2bf(float f) {
    unsigned int u = __float_as_uint(f);
    u = (u + 0x7fffu + ((u >> 16) & 1u)) >> 16;
    return (unsigned short)u;
}
static __device__ __forceinline__ float bf2f(unsigned short h) {
    return __uint_as_float(((unsigned int)h) << 16);
}

// ---------------- fused prep: degree+rank histogram + split x (8 floats/thr) + weight casts ----
__global__ void prep_deg_kernel(const int* __restrict__ dst, int* __restrict__ deg,
                                int* __restrict__ rank,
                                const float* __restrict__ x,
                                const float* __restrict__ W1l, const float* __restrict__ W1r,
                                const float* __restrict__ W2l, const float* __restrict__ W2r,
                                const float* __restrict__ Wlin,
                                unsigned short* __restrict__ xhi, unsigned short* __restrict__ xlo,
                                unsigned short* __restrict__ W1hi, unsigned short* __restrict__ W1lo,
                                unsigned short* __restrict__ W2hi, unsigned short* __restrict__ W2lo,
                                unsigned short* __restrict__ WLhi, unsigned short* __restrict__ WLlo) {
    int b = blockIdx.x, tid = threadIdx.x;
    if (b < 3125) {
        int e = b * 256 + tid;
        rank[e] = atomicAdd(&deg[dst[e]], 1);   // rank within dst bucket
    } else if (b < 6250) {
        int i = ((b - 3125) * 256 + tid) * 8;
        float4 v0 = *(const float4*)(x + i);
        float4 v1 = *(const float4*)(x + i + 4);
        ushort4 h0, l0, h1, l1;
        h0.x = f2bf(v0.x); l0.x = f2bf(v0.x - bf2f(h0.x));
        h0.y = f2bf(v0.y); l0.y = f2bf(v0.y - bf2f(h0.y));
        h0.z = f2bf(v0.z); l0.z = f2bf(v0.z - bf2f(h0.z));
        h0.w = f2bf(v0.w); l0.w = f2bf(v0.w - bf2f(h0.w));
        h1.x = f2bf(v1.x); l1.x = f2bf(v1.x - bf2f(h1.x));
        h1.y = f2bf(v1.y); l1.y = f2bf(v1.y - bf2f(h1.y));
        h1.z = f2bf(v1.z); l1.z = f2bf(v1.z - bf2f(h1.z));
        h1.w = f2bf(v1.w); l1.w = f2bf(v1.w - bf2f(h1.w));
        *(ushort4*)(xhi + i)     = h0;
        *(ushort4*)(xhi + i + 4) = h1;
        *(ushort4*)(xlo + i)     = l0;
        *(ushort4*)(xlo + i + 4) = l1;
    } else if (b < 6378) {
        int isW2 = (b >= 6314);
        const float* A = isW2 ? W2l : W1l;
        const float* B = isW2 ? W2r : W1r;
        unsigned short* hi = isW2 ? W2hi : W1hi;
        unsigned short* lo = isW2 ? W2lo : W1lo;
        int f = (b - (isW2 ? 6314 : 6250)) * 2 + (tid >> 7);
        int t = tid & 127;
        float va = A[f * 128 + t], vb = B[f * 128 + t];
        unsigned short ha = f2bf(va), hb = f2bf(vb);
        hi[f * 256 + t]       = ha;
        hi[f * 256 + 128 + t] = hb;
        lo[f * 256 + t]       = f2bf(va - bf2f(ha));
        lo[f * 256 + 128 + t] = f2bf(vb - bf2f(hb));
    } else {
        int f = b - 6378;
        float v = (f < 40) ? Wlin[f * 256 + tid] : 0.f;
        unsigned short h = f2bf(v);
        WLhi[f * 256 + tid] = h;
        WLlo[f * 256 + tid] = f2bf(v - bf2f(h));
    }
}

// ---------------- single-pass bucket-start allocation (replaces 2-kernel scan) ----------------
// Buckets need NOT be node-ordered: gather only needs [start[n], start[n]+deg[n]).
// Per-block exclusive scan + one atomicAdd(cursor, blockTotal) for the base.
__global__ void scan_alloc(const int* __restrict__ deg, int* __restrict__ cursor,
                           int* __restrict__ startp) {
    __shared__ int wt[4];
    __shared__ int bbase;
    int tid = threadIdx.x, lane = tid & 63, wv = tid >> 6;
    int idx = blockIdx.x * 256 + tid;
    int v = (idx < N_NODES) ? deg[idx] : 0;
    int s = v;
    #pragma unroll
    for (int o = 1; o < 64; o <<= 1) { int t = __shfl_up(s, o, 64); if (lane >= o) s += t; }
    if (lane == 63) wt[wv] = s;
    __syncthreads();
    if (tid == 0) bbase = atomicAdd(cursor, wt[0] + wt[1] + wt[2] + wt[3]);
    __syncthreads();
    int boff = bbase;
    #pragma unroll
    for (int w = 0; w < 4; w++) boff += (w < wv) ? wt[w] : 0;
    if (idx < N_NODES) startp[idx] = boff + s - v;
}

// ---------------- bucket edges by dst (atomic-free: pos = start[dst] + rank) ----------------
__global__ void bucket_kernel(const int* __restrict__ src, const int* __restrict__ dst,
                              const int* __restrict__ startp, const int* __restrict__ rank,
                              int* __restrict__ srcs_sorted) {
    int e = blockIdx.x * blockDim.x + threadIdx.x;
    if (e < N_EDGES) {
        srcs_sorted[startp[dst[e]] + rank[e]] = src[e];
    }
}

// ---------------- gather-mean kernel (no LDS -> 32 waves/CU) ----------------
__global__ __launch_bounds__(256, 8) void gather_mean(
    const int* __restrict__ srcs, const int* __restrict__ startp, const int* __restrict__ deg,
    const unsigned short* __restrict__ Shi,
    unsigned short* __restrict__ Aghi, unsigned short* __restrict__ Aglo)
{
    const int tid = threadIdx.x;
    const int wv = tid >> 6, lane = tid & 63;
    const int g = lane >> 4, q = lane & 15;
    const int qb = q << 4;
    const char* xb = (const char*)Shi;          // row = 256 bytes
    const int wid = blockIdx.x * 4 + wv;
    const int NW = GATHER_BLOCKS * 4;
    #pragma unroll 1
    for (int p = wid; p < N_NODES / 2; p += NW) {
        const int nA = 2 * p, nB = 2 * p + 1;
        const int begA = startp[nA], degA = deg[nA];
        const int begB = startp[nB], degB = deg[nB];
        const int endA = begA + degA, endB = begB + degB;
        float ax[4] = {0,0,0,0}, ay[4] = {0,0,0,0};
        float bx[4] = {0,0,0,0}, by[4] = {0,0,0,0};
        int nsA = (degA + 63) >> 6, nsB = (degB + 63) >> 6;
        int nsmax = max(nsA, nsB);
        #pragma unroll 1
        for (int st = 0; st < nsmax; st++) {
            int svA = 0, svB = 0, nbA = 0, nbB = 0;
            if (st < nsA) {                     // wave-uniform branch
                int sb = begA + (st << 6);
                nbA = min(64, endA - sb);
                svA = srcs[min(sb + lane, endA - 1)];   // 64 edge ids, coalesced
            }
            if (st < nsB) {
                int sb = begB + (st << 6);
                nbB = min(64, endB - sb);
                svB = srcs[min(sb + lane, endB - 1)];
            }
            int itA = (nbA + 3) >> 2, itB = (nbB + 3) >> 2;
            int itmax = max(itA, itB);
            #pragma unroll 2
            for (int b = 0; b < itmax; b++) {
                int ei = (b << 2) + g;          // edge slot within strip for this group
                if (b < itA) {                  // wave-uniform
                    unsigned sv = (unsigned)__shfl(svA, ei, 64);
                    u32x4 v = *(const u32x4*)(xb + ((sv << 8) + qb));
                    v.x = (ei < nbA) ? v.x : 0u;
                    v.y = (ei < nbA) ? v.y : 0u;
                    v.z = (ei < nbA) ? v.z : 0u;
                    v.w = (ei < nbA) ? v.w : 0u;
                    ax[0] += __uint_as_float(v.x << 16); ay[0] += __uint_as_float(v.x & 0xffff0000u);
                    ax[1] += __uint_as_float(v.y << 16); ay[1] += __uint_as_float(v.y & 0xffff0000u);
                    ax[2] += __uint_as_float(v.z << 16); ay[2] += __uint_as_float(v.z & 0xffff0000u);
                    ax[3] += __uint_as_float(v.w << 16); ay[3] += __uint_as_float(v.w & 0xffff0000u);
                }
                if (b < itB) {
                    unsigned sv = (unsigned)__shfl(svB, ei, 64);
                    u32x4 v = *(const u32x4*)(xb + ((sv << 8) + qb));
                    v.x = (ei < nbB) ? v.x : 0u;
                    v.y = (ei < nbB) ? v.y : 0u;
                    v.z = (ei < nbB) ? v.z : 0u;
                    v.w = (ei < nbB) ? v.w : 0u;
                    bx[0] += __uint_as_float(v.x << 16); by[0] += __uint_as_float(v.x & 0xffff0000u);
                    bx[1] += __uint_as_float(v.y << 16); by[1] += __uint_as_float(v.y & 0xffff0000u);
                    bx[2] += __uint_as_float(v.z << 16); by[2] += __uint_as_float(v.z & 0xffff0000u);
                    bx[3] += __uint_as_float(v.w << 16); by[3] += __uint_as_float(v.w & 0xffff0000u);
                }
            }
        }
        // cross-group reduce: lanes {l, l^16, l^32, l^48} hold partials of the same features
        #pragma unroll
        for (int d = 0; d < 4; d++) {
            ax[d] += __shfl_xor(ax[d], 16, 64); ax[d] += __shfl_xor(ax[d], 32, 64);
            ay[d] += __shfl_xor(ay[d], 16, 64); ay[d] += __shfl_xor(ay[d], 32, 64);
            bx[d] += __shfl_xor(bx[d], 16, 64); bx[d] += __shfl_xor(bx[d], 32, 64);
            by[d] += __shfl_xor(by[d], 16, 64); by[d] += __shfl_xor(by[d], 32, 64);
        }
        if (g == 0) {   // 16 lanes write one u32x4 per plane per node (coalesced 256 B)
            float invA = 1.0f / fmaxf((float)degA, 1.0f);
            float invB = 1.0f / fmaxf((float)degB, 1.0f);
            u32x4 ha, la, hb, lb;
            #pragma unroll
            for (int d = 0; d < 4; d++) {
                float sx = ax[d] * invA, sy = ay[d] * invA;
                unsigned short h0 = f2bf(sx), h1 = f2bf(sy);
                unsigned short l0 = f2bf(sx - bf2f(h0)), l1 = f2bf(sy - bf2f(h1));
                ha[d] = (unsigned)h0 | ((unsigned)h1 << 16);
                la[d] = (unsigned)l0 | ((unsigned)l1 << 16);
                float tx = bx[d] * invB, ty = by[d] * invB;
                unsigned short h2 = f2bf(tx), h3 = f2bf(ty);
                unsigned short l2 = f2bf(tx - bf2f(h2)), l3 = f2bf(ty - bf2f(h3));
                hb[d] = (unsigned)h2 | ((unsigned)h3 << 16);
                lb[d] = (unsigned)l2 | ((unsigned)l3 << 16);
            }
            *(u32x4*)(Aghi + (size_t)nA * D + q * 8) = ha;
            *(u32x4*)(Aglo + (size_t)nA * D + q * 8) = la;
            *(u32x4*)(Aghi + (size_t)nB * D + q * 8) = hb;
            *(u32x4*)(Aglo + (size_t)nB * D + q * 8) = lb;
        }
    }
}

// ---------------- layer-1 GEMM: persistent f-sliced blocks (round-8, measured 57.3 us) ----
// W slice (32 KB) staged ONCE per block, then a barrier-free tile loop. NO register
// pipelining (round-9's 2-deep ping-pong spilled: VGPR 84 + 110 MB scratch round-trip).
// TLP (4 blocks/CU, fully resident grid) is the latency-hiding mechanism; measured 2.6 TB/s.
__global__ __launch_bounds__(256, 4) void gemm_persist(
    const unsigned short* __restrict__ Aghi, const unsigned short* __restrict__ Aglo,  // agg planes
    const unsigned short* __restrict__ A2hi, const unsigned short* __restrict__ A2lo,  // self planes
    const unsigned short* __restrict__ Whi, const unsigned short* __restrict__ Wlo,    // [128,256]
    const float* __restrict__ bias,
    unsigned short* __restrict__ Ohi, unsigned short* __restrict__ Olo)         // layer out
{
    __shared__ unsigned short Wl[2][8192];              // 32 KB: this block's 32-f slice (hi,lo)

    const int tid = threadIdx.x;
    const int wv = tid >> 6, lane = tid & 63;
    const int m = lane & 15, quad = lane >> 4;
    const int gg = wv & 1, tp = wv >> 1;
    const int fq = blockIdx.x & 3;
    const int chunk = blockIdx.x >> 2;                  // 0..GEMM_CHUNKS-1
    const int f0 = fq * 32;

    // ---- stage this block's W slice ONCE (32 KB) ----
    #pragma unroll
    for (int itS = 0; itS < 8; itS++) {
        int c = tid + itS * 256;                 // 2048 chunks of 16B (2 planes x 1024)
        int plane = c >> 10;
        int w3 = c & 1023;
        int nt = w3 >> 9, w2 = w3 & 511;
        int ks = w2 >> 6, lidx = w2 & 63;
        int mm = lidx >> 2, qq = lidx & 3;
        const unsigned short* base = plane ? Wlo : Whi;
        const unsigned short* gp = base + (size_t)(f0 + nt * 16 + mm) * 256 + ks * 32 + qq * 8;
        *(bf16x8*)&Wl[plane][(size_t)w3 * 8] = *(const bf16x8*)gp;
    }
    __syncthreads();                                    // the ONLY barrier in this kernel

    const int f = f0 + tp * 16 + m;
    const float bv = bias[f];

    // ---- barrier-free tile loop ----
    #pragma unroll 1
    for (int tile = chunk; tile < NTILES; tile += GEMM_CHUNKS) {
        const int nb0 = tile * 32;
        const int nodec = min(nb0 + gg * 16 + m, N_NODES - 1);

        bf16x8 a1h[4], a1l[4], a2h[4], a2l[4];
        {
            const unsigned short* r1h = Aghi + (size_t)nodec * D + quad * 8;
            const unsigned short* r1l = Aglo + (size_t)nodec * D + quad * 8;
            const unsigned short* r2h = A2hi + (size_t)nodec * D + quad * 8;
            const unsigned short* r2l = A2lo + (size_t)nodec * D + quad * 8;
            #pragma unroll
            for (int ks = 0; ks < 4; ks++) {
                a1h[ks] = *(const bf16x8*)(r1h + ks * 32);
                a1l[ks] = *(const bf16x8*)(r1l + ks * 32);
                a2h[ks] = *(const bf16x8*)(r2h + ks * 32);
                a2l[ks] = *(const bf16x8*)(r2l + ks * 32);
            }
        }

        f32x4 acc0 = {0.f, 0.f, 0.f, 0.f};
        f32x4 acc1 = {0.f, 0.f, 0.f, 0.f};
        f32x4 acc2 = {0.f, 0.f, 0.f, 0.f};
        #pragma unroll
        for (int ks = 0; ks < 8; ks++) {
            int idx = (((tp * 8 + ks) << 6) + (m * 4 + quad)) * 8;
            bf16x8 bh = *(const bf16x8*)&Wl[0][idx];
            bf16x8 bl = *(const bf16x8*)&Wl[1][idx];
            bf16x8 ah = (ks < 4) ? a1h[ks] : a2h[ks - 4];
            bf16x8 al = (ks < 4) ? a1l[ks] : a2l[ks - 4];
            acc0 = __builtin_amdgcn_mfma_f32_16x16x32_bf16(ah, bh, acc0, 0, 0, 0);
            acc1 = __builtin_amdgcn_mfma_f32_16x16x32_bf16(ah, bl, acc1, 0, 0, 0);
            acc2 = __builtin_amdgcn_mfma_f32_16x16x32_bf16(al, bh, acc2, 0, 0, 0);
        }
        #pragma unroll
        for (int r = 0; r < 4; r++) {
            int nrow = nb0 + gg * 16 + quad * 4 + r;
            float v = fmaxf((acc0[r] + (acc1[r] + acc2[r])) + bv, 0.f);
            unsigned short h = f2bf(v);
            unsigned short l = f2bf(v - bf2f(h));
            if (nrow < N_NODES) {
                Ohi[(size_t)nrow * D + f] = h;
                Olo[(size_t)nrow * D + f] = l;
            }
        }
    }
}

// ---------------- layer-2 GEMM (round-7 structure): fq loop + FUSED classifier ----------------
// R7/R8 A/B: fused classifier ~free in this latency-bound kernel; standalone costs ~70 us.
__global__ __launch_bounds__(256, 4) void gemm_fused(
    const unsigned short* __restrict__ Aghi, const unsigned short* __restrict__ Aglo,  // agg planes
    const unsigned short* __restrict__ A2hi, const unsigned short* __restrict__ A2lo,  // self planes
    const unsigned short* __restrict__ Whi, const unsigned short* __restrict__ Wlo,    // [128,256]
    const float* __restrict__ bias,
    unsigned short* __restrict__ Ohi, unsigned short* __restrict__ Olo,         // h2 scratch
    const unsigned short* __restrict__ WLhi, const unsigned short* __restrict__ WLlo,  // [48,256]
    const float* __restrict__ blin, float* __restrict__ out)
{
    __shared__ unsigned short Wl[2][8192];              // 32 KB: [0]=Whi stage, [1]=Wlo stage

    const int tid = threadIdx.x;
    const int wv = tid >> 6, lane = tid & 63;
    const int nb0 = blockIdx.x * 32;
    const int m = lane & 15, quad = lane >> 4;
    const int gg = wv & 1, tp = wv >> 1;
    const int nodec = min(nb0 + gg * 16 + m, N_NODES - 1);

    // A1 frags (agg, K 0..127) + A2 frags (self, K 128..255) from global — loaded ONCE
    bf16x8 a1h[4], a1l[4], a2h[4], a2l[4];
    {
        const unsigned short* r1h = Aghi + (size_t)nodec * D + quad * 8;
        const unsigned short* r1l = Aglo + (size_t)nodec * D + quad * 8;
        const unsigned short* r2h = A2hi + (size_t)nodec * D + quad * 8;
        const unsigned short* r2l = A2lo + (size_t)nodec * D + quad * 8;
        #pragma unroll
        for (int ks = 0; ks < 4; ks++) {
            a1h[ks] = *(const bf16x8*)(r1h + ks * 32);
            a1l[ks] = *(const bf16x8*)(r1l + ks * 32);
            a2h[ks] = *(const bf16x8*)(r2h + ks * 32);
            a2l[ks] = *(const bf16x8*)(r2l + ks * 32);
        }
    }

    // ---- GEMM over 4 f-quarters (Whi+Wlo staged 32 KB at a time) ----
    #pragma unroll 1
    for (int fq = 0; fq < 4; fq++) {
        const int f0 = fq * 32;
        if (fq) __syncthreads();
        #pragma unroll
        for (int itS = 0; itS < 8; itS++) {
            int c = tid + itS * 256;                 // 2048 chunks of 16B (2 planes x 1024)
            int plane = c >> 10;
            int w3 = c & 1023;
            int nt = w3 >> 9, w2 = w3 & 511;
            int ks = w2 >> 6, lidx = w2 & 63;
            int mm = lidx >> 2, qq = lidx & 3;
            const unsigned short* base = plane ? Wlo : Whi;
            const unsigned short* gp = base + (size_t)(f0 + nt * 16 + mm) * 256 + ks * 32 + qq * 8;
            *(bf16x8*)&Wl[plane][(size_t)w3 * 8] = *(const bf16x8*)gp;
        }
        __syncthreads();

        int f = f0 + tp * 16 + m;
        f32x4 acc0 = {0.f, 0.f, 0.f, 0.f};
        f32x4 acc1 = {0.f, 0.f, 0.f, 0.f};
        f32x4 acc2 = {0.f, 0.f, 0.f, 0.f};
        #pragma unroll
        for (int ks = 0; ks < 8; ks++) {
            int idx = (((tp * 8 + ks) << 6) + (m * 4 + quad)) * 8;
            bf16x8 bh = *(const bf16x8*)&Wl[0][idx];
            bf16x8 bl = *(const bf16x8*)&Wl[1][idx];
            bf16x8 ah = (ks < 4) ? a1h[ks] : a2h[ks - 4];
            bf16x8 al = (ks < 4) ? a1l[ks] : a2l[ks - 4];
            acc0 = __builtin_amdgcn_mfma_f32_16x16x32_bf16(ah, bh, acc0, 0, 0, 0);
            acc1 = __builtin_amdgcn_mfma_f32_16x16x32_bf16(ah, bl, acc1, 0, 0, 0);
            acc2 = __builtin_amdgcn_mfma_f32_16x16x32_bf16(al, bh, acc2, 0, 0, 0);
        }
        float bv = bias[f];
        #pragma unroll
        for (int r = 0; r < 4; r++) {
            int lrow = gg * 16 + quad * 4 + r;
            int nrow = nb0 + lrow;
            float v = fmaxf((acc0[r] + (acc1[r] + acc2[r])) + bv, 0.f);
            unsigned short h = f2bf(v);
            unsigned short l = f2bf(v - bf2f(h));
            if (nrow < N_NODES) {
                Ohi[(size_t)nrow * D + f] = h;
                Olo[(size_t)nrow * D + f] = l;
            }
        }
    }

    // ---- classifier GEMM (48 cols) + log_softmax; h2 read back from global scratch ----
    __syncthreads();   // this block's h2 writes drained; Wl now dead -> reuse as stats
    float* stats = (float*)Wl;
    bf16x8 a3h[4], a3l[4];
    {
        const unsigned short* r3h = Ohi + (size_t)nodec * D + quad * 8;
        const unsigned short* r3l = Olo + (size_t)nodec * D + quad * 8;
        #pragma unroll
        for (int ks = 0; ks < 4; ks++) {
            a3h[ks] = *(const bf16x8*)(r3h + ks * 32);
            a3l[ks] = *(const bf16x8*)(r3l + ks * 32);
        }
    }
    // tp=0 -> tiles 0,1 (cols 0..31); tp=1 -> tile 2 (cols 32..47)
    const int ntiles = (tp == 0) ? 2 : 1;
    float res[2][4];
    #pragma unroll
    for (int t = 0; t < 2; t++) {
        if (t >= ntiles) break;
        int nt = (tp == 0) ? t : 2;
        int f = nt * 16 + m;
        const unsigned short* whirow = WLhi + (size_t)f * 256 + quad * 8;
        const unsigned short* wlorow = WLlo + (size_t)f * 256 + quad * 8;
        f32x4 acc0 = {0.f, 0.f, 0.f, 0.f};
        f32x4 acc1 = {0.f, 0.f, 0.f, 0.f};
        f32x4 acc2 = {0.f, 0.f, 0.f, 0.f};
        #pragma unroll
        for (int ks = 0; ks < 8; ks++) {
            bf16x8 bh = *(const bf16x8*)(whirow + ks * 32);
            bf16x8 bl = *(const bf16x8*)(wlorow + ks * 32);
            bf16x8 ah = (ks < 4) ? a2h[ks] : a3h[ks - 4];   // A = [h1 | h2]
            bf16x8 al = (ks < 4) ? a2l[ks] : a3l[ks - 4];
            acc0 = __builtin_amdgcn_mfma_f32_16x16x32_bf16(ah, bh, acc0, 0, 0, 0);
            acc1 = __builtin_amdgcn_mfma_f32_16x16x32_bf16(ah, bl, acc1, 0, 0, 0);
            acc2 = __builtin_amdgcn_mfma_f32_16x16x32_bf16(al, bh, acc2, 0, 0, 0);
        }
        float bv = (f < 40) ? blin[f] : 0.f;
        #pragma unroll
        for (int r = 0; r < 4; r++) res[t][r] = (acc0[r] + (acc1[r] + acc2[r])) + bv;
    }
    #pragma unroll
    for (int r = 0; r < 4; r++) {
        float pm = -INFINITY;
        #pragma unroll
        for (int t = 0; t < 2; t++) {
            if (t >= ntiles) break;
            int f = ((tp == 0) ? t : 2) * 16 + m;
            if (f < 40) pm = fmaxf(pm, res[t][r]);
        }
        #pragma unroll
        for (int o = 8; o > 0; o >>= 1) pm = fmaxf(pm, __shfl_xor(pm, o, 64));
        if (m == 0) stats[tp * 64 + gg * 16 + quad * 4 + r] = pm;
    }
    __syncthreads();
    float gm[4];
    #pragma unroll
    for (int r = 0; r < 4; r++) {
        int row = gg * 16 + quad * 4 + r;          // 0..31
        gm[r] = fmaxf(stats[row], stats[64 + row]);
        float ps = 0.f;
        #pragma unroll
        for (int t = 0; t < 2; t++) {
            if (t >= ntiles) break;
            int f = ((tp == 0) ? t : 2) * 16 + m;
            if (f < 40) ps += expf(res[t][r] - gm[r]);
        }
        #pragma unroll
        for (int o = 8; o > 0; o >>= 1) ps += __shfl_xor(ps, o, 64);
        if (m == 0) stats[128 + tp * 64 + row] = ps;
    }
    __syncthreads();
    #pragma unroll
    for (int r = 0; r < 4; r++) {
        int row = gg * 16 + quad * 4 + r;
        int nrow = nb0 + row;
        if (nrow >= N_NODES) continue;
        float lse = gm[r] + logf(stats[128 + row] + stats[192 + row]);
        #pragma unroll
        for (int t = 0; t < 2; t++) {
            if (t >= ntiles) break;
            int f = ((tp == 0) ? t : 2) * 16 + m;
            if (f < 40) out[(size_t)nrow * 40 + f] = res[t][r] - lse;
        }
    }
}

extern "C" void kernel_launch(void* const* d_in, const int* in_sizes, int n_in,
                              void* d_out, int out_size, void* d_ws, size_t ws_size,
                              hipStream_t stream) {
    const float* x     = (const float*)d_in[0];
    const int*   ei    = (const int*)d_in[1];
    const int*   src   = ei;
    const int*   dst   = ei + N_EDGES;
    const float* W1_l  = (const float*)d_in[2];
    const float* b1_l  = (const float*)d_in[3];
    const float* W1_r  = (const float*)d_in[4];
    const float* W2_l  = (const float*)d_in[5];
    const float* b2_l  = (const float*)d_in[6];
    const float* W2_r  = (const float*)d_in[7];
    const float* W_lin = (const float*)d_in[8];
    const float* b_lin = (const float*)d_in[9];
    float* out = (float*)d_out;

    const size_t nd = (size_t)N_NODES * D;
    unsigned short* xhi  = (unsigned short*)d_ws;
    unsigned short* xlo  = xhi + nd;
    unsigned short* h1hi = xlo + nd;
    unsigned short* h1lo = h1hi + nd;
    unsigned short* W1hi = h1lo + nd;                // 128*256 bf16 each
    unsigned short* W1lo = W1hi + 128 * 256;
    unsigned short* W2hi = W1lo + 128 * 256;
    unsigned short* W2lo = W2hi + 128 * 256;
    unsigned short* WLhi = W2lo + 128 * 256;         // 48*256
    unsigned short* WLlo = WLhi + 48 * 256;
    int* deg    = (int*)(WLlo + 48 * 256);           // N_NODES
    int* cursor = deg + N_NODES;                     // 1 (bucket allocation cursor)
    int* startp = cursor + 1;                        // N_NODES (bucket starts)
    int* rank   = startp + N_NODES;                  // N_EDGES
    int* srcs_sorted = rank + N_EDGES;               // N_EDGES
    unsigned short* aghi = (unsigned short*)(srcs_sorted + N_EDGES);  // agg planes
    unsigned short* aglo = aghi + nd;
    unsigned short* h2hi = aglo + nd;                // h2 scratch
    unsigned short* h2lo = h2hi + nd;

    // ---- prep (casts/splits) + degree/rank histogram in one dispatch ----
    hipMemsetAsync(deg, 0, (N_NODES + 1) * sizeof(int), stream);   // deg + cursor
    prep_deg_kernel<<<6426, 256, 0, stream>>>(dst, deg, rank, x, W1_l, W1_r, W2_l, W2_r, W_lin,
                                              xhi, xlo, W1hi, W1lo, W2hi, W2lo, WLhi, WLlo);

    // ---- CSR build: single-pass bucket-start allocation + bucket ----
    scan_alloc<<<NBLK, 256, 0, stream>>>(deg, cursor, startp);
    bucket_kernel<<<(N_EDGES + 255) / 256, 256, 0, stream>>>(src, dst, startp, rank, srcs_sorted);

    // ---- layer 1: persistent gemm (round-8 measured form) ----
    gather_mean<<<GATHER_BLOCKS, 256, 0, stream>>>(srcs_sorted, startp, deg, xhi, aghi, aglo);
    gemm_persist<<<4 * GEMM_CHUNKS, 256, 0, stream>>>(aghi, aglo, xhi, xlo,
                                                      W1hi, W1lo, b1_l, h1hi, h1lo);
    // ---- layer 2 + fused classifier + log_softmax (round-7 measured form) ----
    gather_mean<<<GATHER_BLOCKS, 256, 0, stream>>>(srcs_sorted, startp, deg, h1hi, aghi, aglo);
    gemm_fused<<<NTILES, 256, 0, stream>>>(aghi, aglo, h1hi, h1lo,
                                           W2hi, W2lo, b2_l, h2hi, h2lo,
                                           WLhi, WLlo, b_lin, out);
}

// Round 13
// 304.066 us; speedup vs baseline: 1.0685x; 1.0685x over previous
//
#include <hip/hip_runtime.h>
#include <math.h>

#define N_NODES 50000
#define N_EDGES 800000
#define D 128
#define NBLK 196   // ceil(N_NODES/256)
#define GATHER_BLOCKS 2048
#define NTILES 1563          // ceil(N_NODES/32)

typedef __attribute__((ext_vector_type(8))) short bf16x8;
typedef __attribute__((ext_vector_type(4))) float f32x4;
typedef __attribute__((ext_vector_type(4))) unsigned int u32x4;

static __device__ __forceinline__ unsigned short f2bf(float f) {
    unsigned int u = __float_as_uint(f);
    u = (u + 0x7fffu + ((u >> 16) & 1u)) >> 16;
    return (unsigned short)u;
}
static __device__ __forceinline__ float bf2f(unsigned short h) {
    return __uint_as_float(((unsigned int)h) << 16);
}

// NOTE (round-12 lesson): hipLaunchCooperativeKernel inside this harness's graph capture
// HANGS the container (grid.sync under graph replay). Multi-kernel dispatch only.

// ---------------- fused prep: degree+rank histogram + split x (8 floats/thr) + weight casts ----
__global__ void prep_deg_kernel(const int* __restrict__ dst, int* __restrict__ deg,
                                int* __restrict__ rank,
                                const float* __restrict__ x,
                                const float* __restrict__ W1l, const float* __restrict__ W1r,
                                const float* __restrict__ W2l, const float* __restrict__ W2r,
                                const float* __restrict__ Wlin,
                                unsigned short* __restrict__ xhi, unsigned short* __restrict__ xlo,
                                unsigned short* __restrict__ W1hi, unsigned short* __restrict__ W1lo,
                                unsigned short* __restrict__ W2hi, unsigned short* __restrict__ W2lo,
                                unsigned short* __restrict__ WLhi, unsigned short* __restrict__ WLlo) {
    int b = blockIdx.x, tid = threadIdx.x;
    if (b < 3125) {
        int e = b * 256 + tid;
        rank[e] = atomicAdd(&deg[dst[e]], 1);   // rank within dst bucket
    } else if (b < 6250) {
        int i = ((b - 3125) * 256 + tid) * 8;
        float4 v0 = *(const float4*)(x + i);
        float4 v1 = *(const float4*)(x + i + 4);
        ushort4 h0, l0, h1, l1;
        h0.x = f2bf(v0.x); l0.x = f2bf(v0.x - bf2f(h0.x));
        h0.y = f2bf(v0.y); l0.y = f2bf(v0.y - bf2f(h0.y));
        h0.z = f2bf(v0.z); l0.z = f2bf(v0.z - bf2f(h0.z));
        h0.w = f2bf(v0.w); l0.w = f2bf(v0.w - bf2f(h0.w));
        h1.x = f2bf(v1.x); l1.x = f2bf(v1.x - bf2f(h1.x));
        h1.y = f2bf(v1.y); l1.y = f2bf(v1.y - bf2f(h1.y));
        h1.z = f2bf(v1.z); l1.z = f2bf(v1.z - bf2f(h1.z));
        h1.w = f2bf(v1.w); l1.w = f2bf(v1.w - bf2f(h1.w));
        *(ushort4*)(xhi + i)     = h0;
        *(ushort4*)(xhi + i + 4) = h1;
        *(ushort4*)(xlo + i)     = l0;
        *(ushort4*)(xlo + i + 4) = l1;
    } else if (b < 6378) {
        int isW2 = (b >= 6314);
        const float* A = isW2 ? W2l : W1l;
        const float* B = isW2 ? W2r : W1r;
        unsigned short* hi = isW2 ? W2hi : W1hi;
        unsigned short* lo = isW2 ? W2lo : W1lo;
        int f = (b - (isW2 ? 6314 : 6250)) * 2 + (tid >> 7);
        int t = tid & 127;
        float va = A[f * 128 + t], vb = B[f * 128 + t];
        unsigned short ha = f2bf(va), hb = f2bf(vb);
        hi[f * 256 + t]       = ha;
        hi[f * 256 + 128 + t] = hb;
        lo[f * 256 + t]       = f2bf(va - bf2f(ha));
        lo[f * 256 + 128 + t] = f2bf(vb - bf2f(hb));
    } else {
        int f = b - 6378;
        float v = (f < 40) ? Wlin[f * 256 + tid] : 0.f;
        unsigned short h = f2bf(v);
        WLhi[f * 256 + tid] = h;
        WLlo[f * 256 + tid] = f2bf(v - bf2f(h));
    }
}

// ---------------- single-pass bucket-start allocation (replaces 2-kernel scan) ----------------
// Buckets need NOT be node-ordered: gather only needs [start[n], start[n]+deg[n]).
__global__ void scan_alloc(const int* __restrict__ deg, int* __restrict__ cursor,
                           int* __restrict__ startp) {
    __shared__ int wt[5];
    int tid = threadIdx.x, lane = tid & 63, wv = tid >> 6;
    int idx = blockIdx.x * 256 + tid;
    int v = (idx < N_NODES) ? deg[idx] : 0;
    int s = v;
    #pragma unroll
    for (int o = 1; o < 64; o <<= 1) { int t = __shfl_up(s, o, 64); if (lane >= o) s += t; }
    if (lane == 63) wt[wv] = s;
    __syncthreads();
    if (tid == 0) wt[4] = atomicAdd(cursor, wt[0] + wt[1] + wt[2] + wt[3]);
    __syncthreads();
    int boff = wt[4];
    #pragma unroll
    for (int w = 0; w < 4; w++) boff += (w < wv) ? wt[w] : 0;
    if (idx < N_NODES) startp[idx] = boff + s - v;
}

// ---------------- bucket edges by dst (atomic-free: pos = start[dst] + rank) ----------------
__global__ void bucket_kernel(const int* __restrict__ src, const int* __restrict__ dst,
                              const int* __restrict__ startp, const int* __restrict__ rank,
                              int* __restrict__ srcs_sorted) {
    int e = blockIdx.x * blockDim.x + threadIdx.x;
    if (e < N_EDGES) {
        srcs_sorted[startp[dst[e]] + rank[e]] = src[e];
    }
}

// ---------------- gather-mean kernel (no LDS -> 32 waves/CU) ----------------
__global__ __launch_bounds__(256, 8) void gather_mean(
    const int* __restrict__ srcs, const int* __restrict__ startp, const int* __restrict__ deg,
    const unsigned short* __restrict__ Shi,
    unsigned short* __restrict__ Aghi, unsigned short* __restrict__ Aglo)
{
    const int tid = threadIdx.x;
    const int wv = tid >> 6, lane = tid & 63;
    const int g = lane >> 4, q = lane & 15;
    const int qb = q << 4;
    const char* xb = (const char*)Shi;          // row = 256 bytes
    const int wid = blockIdx.x * 4 + wv;
    const int NW = GATHER_BLOCKS * 4;
    #pragma unroll 1
    for (int p = wid; p < N_NODES / 2; p += NW) {
        const int nA = 2 * p, nB = 2 * p + 1;
        const int begA = startp[nA], degA = deg[nA];
        const int begB = startp[nB], degB = deg[nB];
        const int endA = begA + degA, endB = begB + degB;
        float ax[4] = {0,0,0,0}, ay[4] = {0,0,0,0};
        float bx[4] = {0,0,0,0}, by[4] = {0,0,0,0};
        int nsA = (degA + 63) >> 6, nsB = (degB + 63) >> 6;
        int nsmax = max(nsA, nsB);
        #pragma unroll 1
        for (int st = 0; st < nsmax; st++) {
            int svA = 0, svB = 0, nbA = 0, nbB = 0;
            if (st < nsA) {                     // wave-uniform branch
                int sb = begA + (st << 6);
                nbA = min(64, endA - sb);
                svA = srcs[min(sb + lane, endA - 1)];   // 64 edge ids, coalesced
            }
            if (st < nsB) {
                int sb = begB + (st << 6);
                nbB = min(64, endB - sb);
                svB = srcs[min(sb + lane, endB - 1)];
            }
            int itA = (nbA + 3) >> 2, itB = (nbB + 3) >> 2;
            int itmax = max(itA, itB);
            #pragma unroll 2
            for (int b = 0; b < itmax; b++) {
                int ei = (b << 2) + g;
                if (b < itA) {
                    unsigned sv = (unsigned)__shfl(svA, ei, 64);
                    u32x4 v = *(const u32x4*)(xb + ((sv << 8) + qb));
                    v.x = (ei < nbA) ? v.x : 0u;
                    v.y = (ei < nbA) ? v.y : 0u;
                    v.z = (ei < nbA) ? v.z : 0u;
                    v.w = (ei < nbA) ? v.w : 0u;
                    ax[0] += __uint_as_float(v.x << 16); ay[0] += __uint_as_float(v.x & 0xffff0000u);
                    ax[1] += __uint_as_float(v.y << 16); ay[1] += __uint_as_float(v.y & 0xffff0000u);
                    ax[2] += __uint_as_float(v.z << 16); ay[2] += __uint_as_float(v.z & 0xffff0000u);
                    ax[3] += __uint_as_float(v.w << 16); ay[3] += __uint_as_float(v.w & 0xffff0000u);
                }
                if (b < itB) {
                    unsigned sv = (unsigned)__shfl(svB, ei, 64);
                    u32x4 v = *(const u32x4*)(xb + ((sv << 8) + qb));
                    v.x = (ei < nbB) ? v.x : 0u;
                    v.y = (ei < nbB) ? v.y : 0u;
                    v.z = (ei < nbB) ? v.z : 0u;
                    v.w = (ei < nbB) ? v.w : 0u;
                    bx[0] += __uint_as_float(v.x << 16); by[0] += __uint_as_float(v.x & 0xffff0000u);
                    bx[1] += __uint_as_float(v.y << 16); by[1] += __uint_as_float(v.y & 0xffff0000u);
                    bx[2] += __uint_as_float(v.z << 16); by[2] += __uint_as_float(v.z & 0xffff0000u);
                    bx[3] += __uint_as_float(v.w << 16); by[3] += __uint_as_float(v.w & 0xffff0000u);
                }
            }
        }
        // cross-group reduce
        #pragma unroll
        for (int d = 0; d < 4; d++) {
            ax[d] += __shfl_xor(ax[d], 16, 64); ax[d] += __shfl_xor(ax[d], 32, 64);
            ay[d] += __shfl_xor(ay[d], 16, 64); ay[d] += __shfl_xor(ay[d], 32, 64);
            bx[d] += __shfl_xor(bx[d], 16, 64); bx[d] += __shfl_xor(bx[d], 32, 64);
            by[d] += __shfl_xor(by[d], 16, 64); by[d] += __shfl_xor(by[d], 32, 64);
        }
        if (g == 0) {
            float invA = 1.0f / fmaxf((float)degA, 1.0f);
            float invB = 1.0f / fmaxf((float)degB, 1.0f);
            u32x4 ha, la, hb, lb;
            #pragma unroll
            for (int d = 0; d < 4; d++) {
                float sx = ax[d] * invA, sy = ay[d] * invA;
                unsigned short h0 = f2bf(sx), h1 = f2bf(sy);
                unsigned short l0 = f2bf(sx - bf2f(h0)), l1 = f2bf(sy - bf2f(h1));
                ha[d] = (unsigned)h0 | ((unsigned)h1 << 16);
                la[d] = (unsigned)l0 | ((unsigned)l1 << 16);
                float tx = bx[d] * invB, ty = by[d] * invB;
                unsigned short h2 = f2bf(tx), h3 = f2bf(ty);
                unsigned short l2 = f2bf(tx - bf2f(h2)), l3 = f2bf(ty - bf2f(h3));
                hb[d] = (unsigned)h2 | ((unsigned)h3 << 16);
                lb[d] = (unsigned)l2 | ((unsigned)l3 << 16);
            }
            *(u32x4*)(Aghi + (size_t)nA * D + q * 8) = ha;
            *(u32x4*)(Aglo + (size_t)nA * D + q * 8) = la;
            *(u32x4*)(Aghi + (size_t)nB * D + q * 8) = hb;
            *(u32x4*)(Aglo + (size_t)nB * D + q * 8) = lb;
        }
    }
}

// ---------------- GEMM layer (round-7 structure, session-best config at 302.7 us total) ----
// Block = 32 nodes; A frags in regs; Whi+Wlo staged 32 KB per f-quarter; FINAL fuses the
// classifier+log_softmax (measured ~free here vs ~70 us standalone). h2 via global scratch.
template<bool FINAL>
__global__ __launch_bounds__(256, 4) void gemm_layer(
    const unsigned short* __restrict__ Aghi, const unsigned short* __restrict__ Aglo,  // agg planes
    const unsigned short* __restrict__ A2hi, const unsigned short* __restrict__ A2lo,  // self planes
    const unsigned short* __restrict__ Whi, const unsigned short* __restrict__ Wlo,    // [128,256]
    const float* __restrict__ bias,
    unsigned short* __restrict__ Ohi, unsigned short* __restrict__ Olo,         // layer out / h2 scratch
    const unsigned short* __restrict__ WLhi, const unsigned short* __restrict__ WLlo,  // [48,256]
    const float* __restrict__ blin, float* __restrict__ out)
{
    __shared__ unsigned short Wl[2][8192];              // 32 KB: [0]=Whi stage, [1]=Wlo stage

    const int tid = threadIdx.x;
    const int wv = tid >> 6, lane = tid & 63;
    const int nb0 = blockIdx.x * 32;
    const int m = lane & 15, quad = lane >> 4;
    const int gg = wv & 1, tp = wv >> 1;
    const int nodec = min(nb0 + gg * 16 + m, N_NODES - 1);

    // A1 frags (agg, K 0..127) + A2 frags (self, K 128..255) from global — loaded ONCE
    bf16x8 a1h[4], a1l[4], a2h[4], a2l[4];
    {
        const unsigned short* r1h = Aghi + (size_t)nodec * D + quad * 8;
        const unsigned short* r1l = Aglo + (size_t)nodec * D + quad * 8;
        const unsigned short* r2h = A2hi + (size_t)nodec * D + quad * 8;
        const unsigned short* r2l = A2lo + (size_t)nodec * D + quad * 8;
        #pragma unroll
        for (int ks = 0; ks < 4; ks++) {
            a1h[ks] = *(const bf16x8*)(r1h + ks * 32);
            a1l[ks] = *(const bf16x8*)(r1l + ks * 32);
            a2h[ks] = *(const bf16x8*)(r2h + ks * 32);
            a2l[ks] = *(const bf16x8*)(r2l + ks * 32);
        }
    }

    // ---- GEMM over 4 f-quarters (Whi+Wlo staged 32 KB at a time) ----
    #pragma unroll 1
    for (int fq = 0; fq < 4; fq++) {
        const int f0 = fq * 32;
        if (fq) __syncthreads();
        #pragma unroll
        for (int itS = 0; itS < 8; itS++) {
            int c = tid + itS * 256;                 // 2048 chunks of 16B (2 planes x 1024)
            int plane = c >> 10;
            int w3 = c & 1023;
            int nt = w3 >> 9, w2 = w3 & 511;
            int ks = w2 >> 6, lidx = w2 & 63;
            int mm = lidx >> 2, qq = lidx & 3;
            const unsigned short* base = plane ? Wlo : Whi;
            const unsigned short* gp = base + (size_t)(f0 + nt * 16 + mm) * 256 + ks * 32 + qq * 8;
            *(bf16x8*)&Wl[plane][(size_t)w3 * 8] = *(const bf16x8*)gp;
        }
        __syncthreads();

        int f = f0 + tp * 16 + m;
        f32x4 acc0 = {0.f, 0.f, 0.f, 0.f};
        f32x4 acc1 = {0.f, 0.f, 0.f, 0.f};
        f32x4 acc2 = {0.f, 0.f, 0.f, 0.f};
        #pragma unroll
        for (int ks = 0; ks < 8; ks++) {
            int idx = (((tp * 8 + ks) << 6) + (m * 4 + quad)) * 8;
            bf16x8 bh = *(const bf16x8*)&Wl[0][idx];
            bf16x8 bl = *(const bf16x8*)&Wl[1][idx];
            bf16x8 ah = (ks < 4) ? a1h[ks] : a2h[ks - 4];
            bf16x8 al = (ks < 4) ? a1l[ks] : a2l[ks - 4];
            acc0 = __builtin_amdgcn_mfma_f32_16x16x32_bf16(ah, bh, acc0, 0, 0, 0);
            acc1 = __builtin_amdgcn_mfma_f32_16x16x32_bf16(ah, bl, acc1, 0, 0, 0);
            acc2 = __builtin_amdgcn_mfma_f32_16x16x32_bf16(al, bh, acc2, 0, 0, 0);
        }
        float bv = bias[f];
        #pragma unroll
        for (int r = 0; r < 4; r++) {
            int lrow = gg * 16 + quad * 4 + r;
            int nrow = nb0 + lrow;
            float v = fmaxf((acc0[r] + (acc1[r] + acc2[r])) + bv, 0.f);
            unsigned short h = f2bf(v);
            unsigned short l = f2bf(v - bf2f(h));
            if (nrow < N_NODES) {
                Ohi[(size_t)nrow * D + f] = h;
                Olo[(size_t)nrow * D + f] = l;
            }
        }
    }

    if (!FINAL) return;

    // ---- classifier GEMM (48 cols) + log_softmax; h2 read back from global scratch ----
    __syncthreads();   // this block's h2 writes drained; Wl now dead -> reuse as stats
    float* stats = (float*)Wl;
    bf16x8 a3h[4], a3l[4];
    {
        const unsigned short* r3h = Ohi + (size_t)nodec * D + quad * 8;
        const unsigned short* r3l = Olo + (size_t)nodec * D + quad * 8;
        #pragma unroll
        for (int ks = 0; ks < 4; ks++) {
            a3h[ks] = *(const bf16x8*)(r3h + ks * 32);
            a3l[ks] = *(const bf16x8*)(r3l + ks * 32);
        }
    }
    // tp=0 -> tiles 0,1 (cols 0..31); tp=1 -> tile 2 (cols 32..47)
    const int ntiles = (tp == 0) ? 2 : 1;
    float res[2][4];
    #pragma unroll
    for (int t = 0; t < 2; t++) {
        if (t >= ntiles) break;
        int nt = (tp == 0) ? t : 2;
        int f = nt * 16 + m;
        const unsigned short* whirow = WLhi + (size_t)f * 256 + quad * 8;
        const unsigned short* wlorow = WLlo + (size_t)f * 256 + quad * 8;
        f32x4 acc0 = {0.f, 0.f, 0.f, 0.f};
        f32x4 acc1 = {0.f, 0.f, 0.f, 0.f};
        f32x4 acc2 = {0.f, 0.f, 0.f, 0.f};
        #pragma unroll
        for (int ks = 0; ks < 8; ks++) {
            bf16x8 bh = *(const bf16x8*)(whirow + ks * 32);
            bf16x8 bl = *(const bf16x8*)(wlorow + ks * 32);
            bf16x8 ah = (ks < 4) ? a2h[ks] : a3h[ks - 4];   // A = [h1 | h2]
            bf16x8 al = (ks < 4) ? a2l[ks] : a3l[ks - 4];
            acc0 = __builtin_amdgcn_mfma_f32_16x16x32_bf16(ah, bh, acc0, 0, 0, 0);
            acc1 = __builtin_amdgcn_mfma_f32_16x16x32_bf16(ah, bl, acc1, 0, 0, 0);
            acc2 = __builtin_amdgcn_mfma_f32_16x16x32_bf16(al, bh, acc2, 0, 0, 0);
        }
        float bv = (f < 40) ? blin[f] : 0.f;
        #pragma unroll
        for (int r = 0; r < 4; r++) res[t][r] = (acc0[r] + (acc1[r] + acc2[r])) + bv;
    }
    #pragma unroll
    for (int r = 0; r < 4; r++) {
        float pm = -INFINITY;
        #pragma unroll
        for (int t = 0; t < 2; t++) {
            if (t >= ntiles) break;
            int f = ((tp == 0) ? t : 2) * 16 + m;
            if (f < 40) pm = fmaxf(pm, res[t][r]);
        }
        #pragma unroll
        for (int o = 8; o > 0; o >>= 1) pm = fmaxf(pm, __shfl_xor(pm, o, 64));
        if (m == 0) stats[tp * 64 + gg * 16 + quad * 4 + r] = pm;
    }
    __syncthreads();
    float gm[4];
    #pragma unroll
    for (int r = 0; r < 4; r++) {
        int row = gg * 16 + quad * 4 + r;          // 0..31
        gm[r] = fmaxf(stats[row], stats[64 + row]);
        float ps = 0.f;
        #pragma unroll
        for (int t = 0; t < 2; t++) {
            if (t >= ntiles) break;
            int f = ((tp == 0) ? t : 2) * 16 + m;
            if (f < 40) ps += expf(res[t][r] - gm[r]);
        }
        #pragma unroll
        for (int o = 8; o > 0; o >>= 1) ps += __shfl_xor(ps, o, 64);
        if (m == 0) stats[128 + tp * 64 + row] = ps;
    }
    __syncthreads();
    #pragma unroll
    for (int r = 0; r < 4; r++) {
        int row = gg * 16 + quad * 4 + r;
        int nrow = nb0 + row;
        if (nrow >= N_NODES) continue;
        float lse = gm[r] + logf(stats[128 + row] + stats[192 + row]);
        #pragma unroll
        for (int t = 0; t < 2; t++) {
            if (t >= ntiles) break;
            int f = ((tp == 0) ? t : 2) * 16 + m;
            if (f < 40) out[(size_t)nrow * 40 + f] = res[t][r] - lse;
        }
    }
}

extern "C" void kernel_launch(void* const* d_in, const int* in_sizes, int n_in,
                              void* d_out, int out_size, void* d_ws, size_t ws_size,
                              hipStream_t stream) {
    const float* x     = (const float*)d_in[0];
    const int*   ei    = (const int*)d_in[1];
    const int*   src   = ei;
    const int*   dst   = ei + N_EDGES;
    const float* W1_l  = (const float*)d_in[2];
    const float* b1_l  = (const float*)d_in[3];
    const float* W1_r  = (const float*)d_in[4];
    const float* W2_l  = (const float*)d_in[5];
    const float* b2_l  = (const float*)d_in[6];
    const float* W2_r  = (const float*)d_in[7];
    const float* W_lin = (const float*)d_in[8];
    const float* b_lin = (const float*)d_in[9];
    float* out = (float*)d_out;

    const size_t nd = (size_t)N_NODES * D;
    unsigned short* xhi  = (unsigned short*)d_ws;
    unsigned short* xlo  = xhi + nd;
    unsigned short* h1hi = xlo + nd;
    unsigned short* h1lo = h1hi + nd;
    unsigned short* W1hi = h1lo + nd;                // 128*256 bf16 each
    unsigned short* W1lo = W1hi + 128 * 256;
    unsigned short* W2hi = W1lo + 128 * 256;
    unsigned short* W2lo = W2hi + 128 * 256;
    unsigned short* WLhi = W2lo + 128 * 256;         // 48*256
    unsigned short* WLlo = WLhi + 48 * 256;
    int* deg    = (int*)(WLlo + 48 * 256);           // N_NODES
    int* cursor = deg + N_NODES;                     // 1
    int* startp = cursor + 1;                        // N_NODES
    int* rank   = startp + N_NODES;                  // N_EDGES
    int* srcs_sorted = rank + N_EDGES;               // N_EDGES
    unsigned short* aghi = (unsigned short*)(srcs_sorted + N_EDGES);  // agg planes
    unsigned short* aglo = aghi + nd;
    unsigned short* h2hi = aglo + nd;                // h2 scratch
    unsigned short* h2lo = h2hi + nd;

    // ---- prep (casts/splits) + degree/rank histogram in one dispatch ----
    hipMemsetAsync(deg, 0, (N_NODES + 1) * sizeof(int), stream);   // deg + cursor
    prep_deg_kernel<<<6426, 256, 0, stream>>>(dst, deg, rank, x, W1_l, W1_r, W2_l, W2_r, W_lin,
                                              xhi, xlo, W1hi, W1lo, W2hi, W2lo, WLhi, WLlo);

    // ---- CSR build: single-pass bucket-start allocation + bucket ----
    scan_alloc<<<NBLK, 256, 0, stream>>>(deg, cursor, startp);
    bucket_kernel<<<(N_EDGES + 255) / 256, 256, 0, stream>>>(src, dst, startp, rank, srcs_sorted);

    // ---- layer 1 ----
    gather_mean<<<GATHER_BLOCKS, 256, 0, stream>>>(srcs_sorted, startp, deg, xhi, aghi, aglo);
    gemm_layer<false><<<NTILES, 256, 0, stream>>>(aghi, aglo, xhi, xlo,
                                                  W1hi, W1lo, b1_l, h1hi, h1lo,
                                                  nullptr, nullptr, nullptr, nullptr);
    // ---- layer 2 + fused classifier + log_softmax ----
    gather_mean<<<GATHER_BLOCKS, 256, 0, stream>>>(srcs_sorted, startp, deg, h1hi, aghi, aglo);
    gemm_layer<true><<<NTILES, 256, 0, stream>>>(aghi, aglo, h1hi, h1lo,
                                                 W2hi, W2lo, b2_l, h2hi, h2lo,
                                                 WLhi, WLlo, b_lin, out);
}